// Round 13
// baseline (399.026 us; speedup 1.0000x reference)
//
#include <hip/hip_runtime.h>
#include <hip/hip_fp16.h>
#include <math.h>

#define NFEAT 256
#define HID 64
#define NCLS 6
#define NBMX 1600       // LDS sizing (nbuck = 1563)
#define CAPB 4096       // k_build LDS buffer bound (bucket mean 2048, 8+ sd headroom)
#define CHUNK 16384     // edges per count/scatter block
#define FUSED_LDS 32768 // gemm branch 32KB; scatter branch needs 12.8KB

typedef float vf4 __attribute__((ext_vector_type(4)));
typedef int   vi4 __attribute__((ext_vector_type(4)));

// ---------------- pass 1: per-block bucket histogram ----------------

__global__ __launch_bounds__(256) void k_count(const int* __restrict__ dst,
                                               int* __restrict__ C, int E, int nbuck) {
  __shared__ int cnt[NBMX];
  int t = threadIdx.x;
  for (int i = t; i < nbuck; i += 256) cnt[i] = 0;
  __syncthreads();
  int e0 = blockIdx.x * CHUNK;
  int e1 = e0 + CHUNK;
  if (e1 > E) e1 = E;
  for (int r0 = e0; r0 < e1; r0 += 1024) {
    int i0 = r0 + t * 4;
    if (i0 + 4 <= e1) {
      vi4 dv = __builtin_nontemporal_load((const vi4*)&dst[i0]);
      atomicAdd(&cnt[dv.x >> 6], 1);
      atomicAdd(&cnt[dv.y >> 6], 1);
      atomicAdd(&cnt[dv.z >> 6], 1);
      atomicAdd(&cnt[dv.w >> 6], 1);
    } else {
      for (int q = 0; q < 4; ++q)
        if (i0 + q < e1) atomicAdd(&cnt[dst[i0 + q] >> 6], 1);
    }
  }
  __syncthreads();
  int* Crow = C + (size_t)blockIdx.x * nbuck;
  for (int i = t; i < nbuck; i += 256) Crow[i] = cnt[i];
}

// ---------------- pass 2: column scan of C + bucket bases ----------------
// C[blk][b] <- exclusive prefix over blk (block-local start within bucket b)
// T[b] = bucket total; bbase[b] = exclusive prefix of T.

__global__ __launch_bounds__(256) void k_scan(int* __restrict__ C,
                                              int* __restrict__ T,
                                              int* __restrict__ bbase,
                                              int nblk, int nbuck) {
  __shared__ int sh[256];
  __shared__ int carry;
  int t = threadIdx.x;
  // phase 1: per-bucket running prefix over blocks (in place)
  for (int b = t; b < nbuck; b += 256) {
    int run = 0;
    int blk = 0;
    for (; blk + 4 <= nblk; blk += 4) {
      int c0 = C[(size_t)(blk + 0) * nbuck + b];
      int c1 = C[(size_t)(blk + 1) * nbuck + b];
      int c2 = C[(size_t)(blk + 2) * nbuck + b];
      int c3 = C[(size_t)(blk + 3) * nbuck + b];
      C[(size_t)(blk + 0) * nbuck + b] = run; run += c0;
      C[(size_t)(blk + 1) * nbuck + b] = run; run += c1;
      C[(size_t)(blk + 2) * nbuck + b] = run; run += c2;
      C[(size_t)(blk + 3) * nbuck + b] = run; run += c3;
    }
    for (; blk < nblk; ++blk) {
      int c = C[(size_t)blk * nbuck + b];
      C[(size_t)blk * nbuck + b] = run;
      run += c;
    }
    T[b] = run;
  }
  if (t == 0) carry = 0;
  __syncthreads();
  // phase 2: exclusive scan of T -> bbase
  for (int base = 0; base < nbuck; base += 256) {
    int v = (base + t < nbuck) ? T[base + t] : 0;
    sh[t] = v;
    __syncthreads();
    for (int off = 1; off < 256; off <<= 1) {
      int x = sh[t];
      int y = (t >= off) ? sh[t - off] : 0;
      __syncthreads();
      sh[t] = x + y;
      __syncthreads();
    }
    if (base + t < nbuck) bbase[base + t] = carry + sh[t] - v;
    __syncthreads();
    if (t == 255) carry += sh[255];
    __syncthreads();
  }
}

// ---------------- pass 3 FUSED: scatter (blocks < nbb) || GEMM1 unscaled (blocks >= nbb) ----------------
// scatter: pos = bbase[b] + C[blk][b] + LDS slot -- exact, dense, no global atomics.
// gemm: H16[row] = fp16(X[row,:] @ W1)  (dis folded into k_agg_w later)

__global__ __launch_bounds__(256) void k_fused(const int* __restrict__ src,
                                               const int* __restrict__ dst,
                                               const int* __restrict__ C,
                                               const int* __restrict__ bbase,
                                               unsigned* __restrict__ packed,
                                               int E, int nbuck, int nbb,
                                               const float* __restrict__ X,
                                               const float* __restrict__ W1,
                                               __half* __restrict__ H16, int n) {
  extern __shared__ char smem[];
  int t = threadIdx.x;

  if (blockIdx.x < nbb) {
    // ---------------- scatter branch ----------------
    int* baseL = (int*)smem;            // NBMX: bbase[b] + C[blk][b]
    int* cnt   = baseL + NBMX;          // NBMX: local slot cursor
    const int* Crow = C + (size_t)blockIdx.x * nbuck;
    for (int i = t; i < nbuck; i += 256) {
      baseL[i] = bbase[i] + Crow[i];
      cnt[i] = 0;
    }
    __syncthreads();

    int e0 = blockIdx.x * CHUNK;
    int e1 = e0 + CHUNK;
    if (e1 > E) e1 = E;
    for (int r0 = e0; r0 < e1; r0 += 1024) {
      int i0 = r0 + t * 4;
      int s4[4], d4[4];
      bool full = (i0 + 4 <= e1);
      if (full) {
        vi4 sv = __builtin_nontemporal_load((const vi4*)&src[i0]);
        vi4 dv = __builtin_nontemporal_load((const vi4*)&dst[i0]);
        s4[0] = sv.x; s4[1] = sv.y; s4[2] = sv.z; s4[3] = sv.w;
        d4[0] = dv.x; d4[1] = dv.y; d4[2] = dv.z; d4[3] = dv.w;
      } else {
        for (int q = 0; q < 4; ++q)
          if (i0 + q < e1) { s4[q] = src[i0 + q]; d4[q] = dst[i0 + q]; }
      }
#pragma unroll
      for (int q = 0; q < 4; ++q) {
        if (i0 + q < e1) {
          int b = d4[q] >> 6;
          int slot = atomicAdd(&cnt[b], 1);
          packed[(size_t)baseL[b] + slot] =
              ((unsigned)s4[q] << 6) | (unsigned)(d4[q] & 63);
        }
      }
    }
  } else {
    // ---------------- gemm1 branch (K = NFEAT, unscaled fp16 out) ----------------
    float* Wl = (float*)smem;          // 64*64
    float* Xl = Wl + 4096;             // 64*64
    const int row0 = (blockIdx.x - nbb) * 64;
    const int tc = t & 15;
    const int tr = t >> 4;
    float acc[4][4] = {};

    for (int k0 = 0; k0 < NFEAT; k0 += 64) {
      __syncthreads();
#pragma unroll
      for (int i = 0; i < 4; ++i) {
        int idx = t * 4 + i * 1024;
        int kr = idx >> 6, c = idx & 63;
        *(vf4*)&Wl[idx] = *(const vf4*)&W1[(size_t)(k0 + kr) * 64 + c];
      }
#pragma unroll
      for (int i = 0; i < 4; ++i) {
        int idx = t * 4 + i * 1024;
        int r = idx >> 6, c = idx & 63;
        int row = row0 + r;
        vf4 v = {0.f, 0.f, 0.f, 0.f};
        if (row < n) v = __builtin_nontemporal_load((const vf4*)&X[(size_t)row * NFEAT + k0 + c]);
        *(vf4*)&Xl[idx] = v;
      }
      __syncthreads();
#pragma unroll 4
      for (int kk = 0; kk < 64; kk += 4) {
        float4 xv[4], wv[4];
#pragma unroll
        for (int r = 0; r < 4; ++r) xv[r] = *(float4*)&Xl[(tr * 4 + r) * 64 + kk];
#pragma unroll
        for (int q = 0; q < 4; ++q) wv[q] = *(float4*)&Wl[(kk + q) * 64 + tc * 4];
#pragma unroll
        for (int r = 0; r < 4; ++r) {
          const float xr[4] = {xv[r].x, xv[r].y, xv[r].z, xv[r].w};
#pragma unroll
          for (int q = 0; q < 4; ++q) {
            acc[r][0] += xr[q] * wv[q].x;
            acc[r][1] += xr[q] * wv[q].y;
            acc[r][2] += xr[q] * wv[q].z;
            acc[r][3] += xr[q] * wv[q].w;
          }
        }
      }
    }
#pragma unroll
    for (int r = 0; r < 4; ++r) {
      int row = row0 + tr * 4 + r;
      if (row < n) {
        __half2 h01 = __floats2half2_rn(acc[r][0], acc[r][1]);
        __half2 h23 = __floats2half2_rn(acc[r][2], acc[r][3]);
        uint2 st;
        st.x = *reinterpret_cast<unsigned*>(&h01);
        st.y = *reinterpret_cast<unsigned*>(&h23);
        ((uint2*)H16)[(size_t)row * 16 + tc] = st;
      }
    }
  }
}

// ---------------- build: in-LDS counting sort of dense bucket segments ----------------

__global__ __launch_bounds__(256) void k_build(unsigned* __restrict__ packed,
                                               const int* __restrict__ T,
                                               const int* __restrict__ bbase,
                                               int2* __restrict__ rowrange,
                                               float* __restrict__ dis,
                                               int n, int nbuck) {
  __shared__ unsigned buf[CAPB];   // 16KB
  __shared__ unsigned outb[CAPB];  // 16KB
  __shared__ int cnt4[4][64];
  __shared__ int cur4[4][64];
  __shared__ int offi[64];
  __shared__ int offx[64];
  __shared__ int cntl[64];
  int b = blockIdx.x;
  int t = threadIdx.x;
  int g = t >> 6;
  int m = T[b];
  if (m > CAPB) m = CAPB;  // statistically unreachable (mean 2048, 8+ sd)
  int bb = bbase[b];
  unsigned* pb = packed + bb;

  cnt4[g][t & 63] = 0;
  for (int k = t; k < m; k += 256) buf[k] = pb[k];
  __syncthreads();
  for (int k = t; k < m; k += 256) atomicAdd(&cnt4[g][buf[k] & 63u], 1);
  __syncthreads();
  if (t < 64) {
    int c0 = cnt4[0][t], c1 = cnt4[1][t], c2 = cnt4[2][t], c3 = cnt4[3][t];
    int tot = c0 + c1 + c2 + c3;
    cntl[t] = tot;
    offi[t] = tot;
    cur4[0][t] = 0;
    cur4[1][t] = c0;
    cur4[2][t] = c0 + c1;
    cur4[3][t] = c0 + c1 + c2;
  }
  __syncthreads();
  for (int off = 1; off < 64; off <<= 1) {
    int x = (t < 64) ? offi[t] : 0;
    int y = (t >= off && t < 64) ? offi[t - off] : 0;
    __syncthreads();
    if (t < 64) offi[t] = x + y;
    __syncthreads();
  }
  if (t < 64) {
    offx[t] = offi[t] - cntl[t];
    int v = b * 64 + t;
    if (v < n) {
      rowrange[v] = make_int2(bb + offx[t], cntl[t]);
      dis[v] = rsqrtf((float)cntl[t] + 1.0f);  // +1 self-loop
    }
#pragma unroll
    for (int gg = 0; gg < 4; ++gg) cur4[gg][t] += offx[t];
  }
  __syncthreads();
  for (int k = t; k < m; k += 256) {
    unsigned e = buf[k];
    int dl = e & 63u;
    int q = atomicAdd(&cur4[g][dl], 1);
    outb[q] = e >> 6;
  }
  __syncthreads();
  for (int k = t; k < m; k += 256) pb[k] = outb[k];  // in place: packed becomes srcs
}

// ---------------- layer-1 agg: out = relu(dv*(sum dis[s]*h[s] + dv*h[v]) + b) ----------------

__global__ __launch_bounds__(256) void k_agg_w(const int2* __restrict__ rowrange,
                                               const int* __restrict__ srcs,
                                               const __half* __restrict__ g16,
                                               const float* __restrict__ dis,
                                               const float* __restrict__ bias,
                                               float* __restrict__ outp, int n) {
  int v = blockIdx.x * 16 + (threadIdx.x >> 4);
  if (v >= n) return;
  int lane = threadIdx.x & 15;
  int2 rr = rowrange[v];
  int j = rr.x, end = rr.x + rr.y;
  const uint2* g2 = (const uint2*)g16;

  float dv = dis[v];
  uint2 su = g2[(size_t)v * 16 + lane];
  float2 f0 = __half22float2(*reinterpret_cast<__half2*>(&su.x));
  float2 f1 = __half22float2(*reinterpret_cast<__half2*>(&su.y));
  float ax = dv * f0.x, ay = dv * f0.y, az = dv * f1.x, aw = dv * f1.y;

  for (; j + 8 <= end; j += 8) {
    int s[8];
#pragma unroll
    for (int q = 0; q < 8; ++q) s[q] = __builtin_nontemporal_load(&srcs[j + q]);
    float ds[8];
    uint2 a[8];
#pragma unroll
    for (int q = 0; q < 8; ++q) { ds[q] = dis[s[q]]; a[q] = g2[(size_t)s[q] * 16 + lane]; }
#pragma unroll
    for (int q = 0; q < 8; ++q) {
      float2 p0 = __half22float2(*reinterpret_cast<__half2*>(&a[q].x));
      float2 p1 = __half22float2(*reinterpret_cast<__half2*>(&a[q].y));
      ax = fmaf(ds[q], p0.x, ax); ay = fmaf(ds[q], p0.y, ay);
      az = fmaf(ds[q], p1.x, az); aw = fmaf(ds[q], p1.y, aw);
    }
  }
  for (; j < end; ++j) {
    int s0 = __builtin_nontemporal_load(&srcs[j]);
    float ds = dis[s0];
    uint2 a0 = g2[(size_t)s0 * 16 + lane];
    float2 p0 = __half22float2(*reinterpret_cast<__half2*>(&a0.x));
    float2 p1 = __half22float2(*reinterpret_cast<__half2*>(&a0.y));
    ax = fmaf(ds, p0.x, ax); ay = fmaf(ds, p0.y, ay);
    az = fmaf(ds, p1.x, az); aw = fmaf(ds, p1.y, aw);
  }

  float4 bb = *(const float4*)&bias[lane * 4];
  float4 o;
  o.x = fmaxf(fmaf(dv, ax, bb.x), 0.f);
  o.y = fmaxf(fmaf(dv, ay, bb.y), 0.f);
  o.z = fmaxf(fmaf(dv, az, bb.z), 0.f);
  o.w = fmaxf(fmaf(dv, aw, bb.w), 0.f);
  ((float4*)outp)[(size_t)v * 16 + lane] = o;
}

// ---------------- GEMM (layer 2): G16 = fp16(dis * (A @ W)), K=64 ----------------

template<int K>
__global__ __launch_bounds__(256) void k_gemm_scaled(const float* __restrict__ X,
                                                     const float* __restrict__ W,
                                                     const float* __restrict__ dis,
                                                     __half* __restrict__ G16, int n) {
  __shared__ float Wl[64 * 64];
  __shared__ float Xl[64 * 64];
  const int tid = threadIdx.x;
  const int row0 = blockIdx.x * 64;
  const int tc = tid & 15;
  const int tr = tid >> 4;
  float acc[4][4] = {};

  for (int k0 = 0; k0 < K; k0 += 64) {
    __syncthreads();
#pragma unroll
    for (int i = 0; i < 4; ++i) {
      int idx = tid * 4 + i * 1024;
      int kr = idx >> 6, c = idx & 63;
      *(vf4*)&Wl[idx] = *(const vf4*)&W[(size_t)(k0 + kr) * 64 + c];
    }
#pragma unroll
    for (int i = 0; i < 4; ++i) {
      int idx = tid * 4 + i * 1024;
      int r = idx >> 6, c = idx & 63;
      int row = row0 + r;
      vf4 v = {0.f, 0.f, 0.f, 0.f};
      if (row < n) v = __builtin_nontemporal_load((const vf4*)&X[(size_t)row * K + k0 + c]);
      *(vf4*)&Xl[idx] = v;
    }
    __syncthreads();
#pragma unroll 4
    for (int kk = 0; kk < 64; kk += 4) {
      float4 xv[4], wv[4];
#pragma unroll
      for (int r = 0; r < 4; ++r) xv[r] = *(float4*)&Xl[(tr * 4 + r) * 64 + kk];
#pragma unroll
      for (int q = 0; q < 4; ++q) wv[q] = *(float4*)&Wl[(kk + q) * 64 + tc * 4];
#pragma unroll
      for (int r = 0; r < 4; ++r) {
        const float xr[4] = {xv[r].x, xv[r].y, xv[r].z, xv[r].w};
#pragma unroll
        for (int q = 0; q < 4; ++q) {
          acc[r][0] += xr[q] * wv[q].x;
          acc[r][1] += xr[q] * wv[q].y;
          acc[r][2] += xr[q] * wv[q].z;
          acc[r][3] += xr[q] * wv[q].w;
        }
      }
    }
  }
#pragma unroll
  for (int r = 0; r < 4; ++r) {
    int row = row0 + tr * 4 + r;
    if (row < n) {
      float s = dis[row];
      __half2 h01 = __floats2half2_rn(acc[r][0] * s, acc[r][1] * s);
      __half2 h23 = __floats2half2_rn(acc[r][2] * s, acc[r][3] * s);
      uint2 st;
      st.x = *reinterpret_cast<unsigned*>(&h01);
      st.y = *reinterpret_cast<unsigned*>(&h23);
      ((uint2*)G16)[(size_t)row * 16 + tc] = st;
    }
  }
}

// ---------------- layer-2 agg (messages pre-scaled) ----------------

__global__ __launch_bounds__(256) void k_agg_csr(const int2* __restrict__ rowrange,
                                                 const int* __restrict__ srcs,
                                                 const __half* __restrict__ g16,
                                                 const float* __restrict__ dis,
                                                 const float* __restrict__ bias,
                                                 float* __restrict__ outp, int n) {
  int v = blockIdx.x * 16 + (threadIdx.x >> 4);
  if (v >= n) return;
  int lane = threadIdx.x & 15;
  int2 rr = rowrange[v];
  int j = rr.x, end = rr.x + rr.y;
  const uint2* g2 = (const uint2*)g16;

  uint2 su = g2[(size_t)v * 16 + lane];
  float2 f0 = __half22float2(*reinterpret_cast<__half2*>(&su.x));
  float2 f1 = __half22float2(*reinterpret_cast<__half2*>(&su.y));
  float ax = f0.x, ay = f0.y, az = f1.x, aw = f1.y;

  for (; j + 8 <= end; j += 8) {
    int s[8];
#pragma unroll
    for (int q = 0; q < 8; ++q) s[q] = __builtin_nontemporal_load(&srcs[j + q]);
    uint2 a[8];
#pragma unroll
    for (int q = 0; q < 8; ++q) a[q] = g2[(size_t)s[q] * 16 + lane];
#pragma unroll
    for (int q = 0; q < 8; ++q) {
      float2 p0 = __half22float2(*reinterpret_cast<__half2*>(&a[q].x));
      float2 p1 = __half22float2(*reinterpret_cast<__half2*>(&a[q].y));
      ax += p0.x; ay += p0.y; az += p1.x; aw += p1.y;
    }
  }
  for (; j < end; ++j) {
    int s0 = __builtin_nontemporal_load(&srcs[j]);
    uint2 a0 = g2[(size_t)s0 * 16 + lane];
    float2 p0 = __half22float2(*reinterpret_cast<__half2*>(&a0.x));
    float2 p1 = __half22float2(*reinterpret_cast<__half2*>(&a0.y));
    ax += p0.x; ay += p0.y; az += p1.x; aw += p1.y;
  }

  float dv = dis[v];
  float4 bb = *(const float4*)&bias[lane * 4];
  float4 o;
  o.x = fmaxf(fmaf(dv, ax, bb.x), 0.f);
  o.y = fmaxf(fmaf(dv, ay, bb.y), 0.f);
  o.z = fmaxf(fmaf(dv, az, bb.z), 0.f);
  o.w = fmaxf(fmaf(dv, aw, bb.w), 0.f);
  ((float4*)outp)[(size_t)v * 16 + lane] = o;
}

// ---------------- final FC ----------------

__global__ __launch_bounds__(256) void k_fc(const float* __restrict__ A,
                                            const float* __restrict__ Wfc,
                                            const float* __restrict__ bfc,
                                            float* __restrict__ outp, int n) {
  __shared__ float Wl[64 * NCLS];
  __shared__ float bl[8];
  int tid = threadIdx.x;
  for (int i = tid; i < 64 * NCLS; i += 256) Wl[i] = Wfc[i];
  if (tid < NCLS) bl[tid] = bfc[tid];
  __syncthreads();
  int row = blockIdx.x * 256 + tid;
  if (row >= n) return;
  float accv[NCLS];
#pragma unroll
  for (int j = 0; j < NCLS; ++j) accv[j] = bl[j];
  const vf4* a4 = (const vf4*)&A[(size_t)row * 64];
#pragma unroll
  for (int k4 = 0; k4 < 16; ++k4) {
    vf4 a = __builtin_nontemporal_load(&a4[k4]);
    const float av[4] = {a.x, a.y, a.z, a.w};
#pragma unroll
    for (int q = 0; q < 4; ++q)
#pragma unroll
      for (int j = 0; j < NCLS; ++j) accv[j] += av[q] * Wl[(k4 * 4 + q) * NCLS + j];
  }
#pragma unroll
  for (int j = 0; j < NCLS; ++j) outp[(size_t)row * NCLS + j] = accv[j];
}

// ---------------- launch ----------------

extern "C" void kernel_launch(void* const* d_in, const int* in_sizes, int n_in,
                              void* d_out, int out_size, void* d_ws, size_t ws_size,
                              hipStream_t stream) {
  const float* x   = (const float*)d_in[0];
  const int*   ei  = (const int*)d_in[1];
  const float* W1  = (const float*)d_in[2];
  const float* b1  = (const float*)d_in[3];
  const float* W2  = (const float*)d_in[4];
  const float* b2  = (const float*)d_in[5];
  const float* Wfc = (const float*)d_in[6];
  const float* bfc = (const float*)d_in[7];
  float* out = (float*)d_out;

  const int n = in_sizes[0] / NFEAT;   // 100000
  const int E = in_sizes[1] / 2;       // 3200000
  const int* src = ei;
  const int* dst = ei + E;
  const int nbuck = (n + 63) >> 6;     // 1563 (<= NBMX)
  const int nbb = (E + CHUNK - 1) / CHUNK;  // 196 count/scatter blocks
  const int ntile = (n + 63) / 64;     // 1563 gemm tiles

  char* ws = (char*)d_ws;
  size_t off = 0;
  auto alloc = [&](size_t bytes) -> void* {
    void* p = (void*)(ws + off);
    off += (bytes + 255) & ~(size_t)255;
    return p;
  };
  float* dis      = (float*)alloc((size_t)n * 4);
  int2*  rowrange = (int2*)alloc((size_t)n * 8);
  int*   C        = (int*)alloc((size_t)nbb * nbuck * 4);   // 1.2MB count matrix
  int*   T        = (int*)alloc((size_t)nbuck * 4);
  int*   bbase    = (int*)alloc((size_t)nbuck * 4);
  unsigned* packed = (unsigned*)alloc((size_t)E * 4);       // 12.8MB dense; becomes srcs
  __half* bufA16  = (__half*)alloc((size_t)n * HID * 2);    // 12.8MB
  float* bufB     = (float*)alloc((size_t)n * HID * 4);     // 25.6MB

  // ---- deterministic 3-pass CSR build; pass 3 runs || gemm1 ----
  k_count<<<nbb, 256, 0, stream>>>(dst, C, E, nbuck);
  k_scan<<<1, 256, 0, stream>>>(C, T, bbase, nbb, nbuck);
  k_fused<<<nbb + ntile, 256, FUSED_LDS, stream>>>(src, dst, C, bbase, packed,
                                                   E, nbuck, nbb, x, W1, bufA16, n);
  k_build<<<nbuck, 256, 0, stream>>>(packed, T, bbase, rowrange, dis, n, nbuck);

  // ---- layer 1 aggregation (dis-weighted) ----
  k_agg_w<<<(n + 15) / 16, 256, 0, stream>>>(rowrange, (const int*)packed, bufA16, dis, b1, bufB, n);

  // ---- layer 2 ----
  k_gemm_scaled<HID><<<(n + 63) / 64, 256, 0, stream>>>(bufB, W2, dis, bufA16, n);
  k_agg_csr<<<(n + 15) / 16, 256, 0, stream>>>(rowrange, (const int*)packed, bufA16, dis, b2, bufB, n);

  // ---- FC head ----
  k_fc<<<(n + 255) / 256, 256, 0, stream>>>(bufB, Wfc, bfc, out, n);
}

// Round 14
// 317.433 us; speedup vs baseline: 1.2570x; 1.2570x over previous
//
#include <hip/hip_runtime.h>
#include <hip/hip_fp16.h>
#include <math.h>

#define NFEAT 256
#define HID 64
#define NCLS 6
#define NBMX 1600       // LDS sizing (nbuck = 1563)
#define CAPB 4096       // k_build LDS buffer bound (bucket mean 2048, 8+ sd headroom)
#define CHUNK 16384     // edges per count/scatter block
#define FUSED_LDS 32768 // gemm branch 32KB; scatter branch needs 12.8KB

typedef float vf4 __attribute__((ext_vector_type(4)));
typedef int   vi4 __attribute__((ext_vector_type(4)));

// ---------------- pass 1: per-block bucket histogram ----------------

__global__ __launch_bounds__(256) void k_count(const int* __restrict__ dst,
                                               int* __restrict__ C, int E, int nbuck) {
  __shared__ int cnt[NBMX];
  int t = threadIdx.x;
  for (int i = t; i < nbuck; i += 256) cnt[i] = 0;
  __syncthreads();
  int e0 = blockIdx.x * CHUNK;
  int e1 = e0 + CHUNK;
  if (e1 > E) e1 = E;
  for (int r0 = e0; r0 < e1; r0 += 1024) {
    int i0 = r0 + t * 4;
    if (i0 + 4 <= e1) {
      vi4 dv = __builtin_nontemporal_load((const vi4*)&dst[i0]);
      atomicAdd(&cnt[dv.x >> 6], 1);
      atomicAdd(&cnt[dv.y >> 6], 1);
      atomicAdd(&cnt[dv.z >> 6], 1);
      atomicAdd(&cnt[dv.w >> 6], 1);
    } else {
      for (int q = 0; q < 4; ++q)
        if (i0 + q < e1) atomicAdd(&cnt[dst[i0 + q] >> 6], 1);
    }
  }
  __syncthreads();
  int* Crow = C + (size_t)blockIdx.x * nbuck;
  for (int i = t; i < nbuck; i += 256) Crow[i] = cnt[i];
}

// ---------------- pass 2a: per-bucket column prefix over blocks (parallel over buckets) ----------------
// C[blk][b] <- exclusive prefix over blk; T[b] = total. Lane-adjacent b => coalesced.

__global__ __launch_bounds__(256) void k_scan_cols(int* __restrict__ C,
                                                   int* __restrict__ T,
                                                   int nblk, int nbuck) {
  int b = blockIdx.x * 256 + threadIdx.x;
  if (b >= nbuck) return;
  int run = 0;
  int blk = 0;
  for (; blk + 4 <= nblk; blk += 4) {
    int c0 = C[(size_t)(blk + 0) * nbuck + b];
    int c1 = C[(size_t)(blk + 1) * nbuck + b];
    int c2 = C[(size_t)(blk + 2) * nbuck + b];
    int c3 = C[(size_t)(blk + 3) * nbuck + b];
    C[(size_t)(blk + 0) * nbuck + b] = run; run += c0;
    C[(size_t)(blk + 1) * nbuck + b] = run; run += c1;
    C[(size_t)(blk + 2) * nbuck + b] = run; run += c2;
    C[(size_t)(blk + 3) * nbuck + b] = run; run += c3;
  }
  for (; blk < nblk; ++blk) {
    int c = C[(size_t)blk * nbuck + b];
    C[(size_t)blk * nbuck + b] = run;
    run += c;
  }
  T[b] = run;
}

// ---------------- pass 2b: exclusive scan of T -> bbase (small, 1 block) ----------------

__global__ __launch_bounds__(256) void k_scanb(const int* __restrict__ T,
                                               int* __restrict__ bbase, int nbuck) {
  __shared__ int sh[256];
  __shared__ int carry;
  int t = threadIdx.x;
  if (t == 0) carry = 0;
  __syncthreads();
  for (int base = 0; base < nbuck; base += 256) {
    int v = (base + t < nbuck) ? T[base + t] : 0;
    sh[t] = v;
    __syncthreads();
    for (int off = 1; off < 256; off <<= 1) {
      int x = sh[t];
      int y = (t >= off) ? sh[t - off] : 0;
      __syncthreads();
      sh[t] = x + y;
      __syncthreads();
    }
    if (base + t < nbuck) bbase[base + t] = carry + sh[t] - v;
    __syncthreads();
    if (t == 255) carry += sh[255];
    __syncthreads();
  }
}

// ---------------- pass 3 FUSED: scatter (blocks < nbb) || GEMM1 unscaled (blocks >= nbb) ----------------
// scatter: pos = bbase[b] + C[blk][b] + LDS slot -- exact, dense, no global atomics.
// gemm: H16[row] = fp16(X[row,:] @ W1)  (dis folded into k_agg_w later)

__global__ __launch_bounds__(256) void k_fused(const int* __restrict__ src,
                                               const int* __restrict__ dst,
                                               const int* __restrict__ C,
                                               const int* __restrict__ bbase,
                                               unsigned* __restrict__ packed,
                                               int E, int nbuck, int nbb,
                                               const float* __restrict__ X,
                                               const float* __restrict__ W1,
                                               __half* __restrict__ H16, int n) {
  extern __shared__ char smem[];
  int t = threadIdx.x;

  if (blockIdx.x < nbb) {
    // ---------------- scatter branch ----------------
    int* baseL = (int*)smem;            // NBMX: bbase[b] + C[blk][b]
    int* cnt   = baseL + NBMX;          // NBMX: local slot cursor
    const int* Crow = C + (size_t)blockIdx.x * nbuck;
    for (int i = t; i < nbuck; i += 256) {
      baseL[i] = bbase[i] + Crow[i];
      cnt[i] = 0;
    }
    __syncthreads();

    int e0 = blockIdx.x * CHUNK;
    int e1 = e0 + CHUNK;
    if (e1 > E) e1 = E;
    for (int r0 = e0; r0 < e1; r0 += 1024) {
      int i0 = r0 + t * 4;
      int s4[4], d4[4];
      bool full = (i0 + 4 <= e1);
      if (full) {
        vi4 sv = __builtin_nontemporal_load((const vi4*)&src[i0]);
        vi4 dv = __builtin_nontemporal_load((const vi4*)&dst[i0]);
        s4[0] = sv.x; s4[1] = sv.y; s4[2] = sv.z; s4[3] = sv.w;
        d4[0] = dv.x; d4[1] = dv.y; d4[2] = dv.z; d4[3] = dv.w;
      } else {
        for (int q = 0; q < 4; ++q)
          if (i0 + q < e1) { s4[q] = src[i0 + q]; d4[q] = dst[i0 + q]; }
      }
#pragma unroll
      for (int q = 0; q < 4; ++q) {
        if (i0 + q < e1) {
          int b = d4[q] >> 6;
          int slot = atomicAdd(&cnt[b], 1);
          packed[(size_t)baseL[b] + slot] =
              ((unsigned)s4[q] << 6) | (unsigned)(d4[q] & 63);
        }
      }
    }
  } else {
    // ---------------- gemm1 branch (K = NFEAT, unscaled fp16 out) ----------------
    float* Wl = (float*)smem;          // 64*64
    float* Xl = Wl + 4096;             // 64*64
    const int row0 = (blockIdx.x - nbb) * 64;
    const int tc = t & 15;
    const int tr = t >> 4;
    float acc[4][4] = {};

    for (int k0 = 0; k0 < NFEAT; k0 += 64) {
      __syncthreads();
#pragma unroll
      for (int i = 0; i < 4; ++i) {
        int idx = t * 4 + i * 1024;
        int kr = idx >> 6, c = idx & 63;
        *(vf4*)&Wl[idx] = *(const vf4*)&W1[(size_t)(k0 + kr) * 64 + c];
      }
#pragma unroll
      for (int i = 0; i < 4; ++i) {
        int idx = t * 4 + i * 1024;
        int r = idx >> 6, c = idx & 63;
        int row = row0 + r;
        vf4 v = {0.f, 0.f, 0.f, 0.f};
        if (row < n) v = __builtin_nontemporal_load((const vf4*)&X[(size_t)row * NFEAT + k0 + c]);
        *(vf4*)&Xl[idx] = v;
      }
      __syncthreads();
#pragma unroll 4
      for (int kk = 0; kk < 64; kk += 4) {
        float4 xv[4], wv[4];
#pragma unroll
        for (int r = 0; r < 4; ++r) xv[r] = *(float4*)&Xl[(tr * 4 + r) * 64 + kk];
#pragma unroll
        for (int q = 0; q < 4; ++q) wv[q] = *(float4*)&Wl[(kk + q) * 64 + tc * 4];
#pragma unroll
        for (int r = 0; r < 4; ++r) {
          const float xr[4] = {xv[r].x, xv[r].y, xv[r].z, xv[r].w};
#pragma unroll
          for (int q = 0; q < 4; ++q) {
            acc[r][0] += xr[q] * wv[q].x;
            acc[r][1] += xr[q] * wv[q].y;
            acc[r][2] += xr[q] * wv[q].z;
            acc[r][3] += xr[q] * wv[q].w;
          }
        }
      }
    }
#pragma unroll
    for (int r = 0; r < 4; ++r) {
      int row = row0 + tr * 4 + r;
      if (row < n) {
        __half2 h01 = __floats2half2_rn(acc[r][0], acc[r][1]);
        __half2 h23 = __floats2half2_rn(acc[r][2], acc[r][3]);
        uint2 st;
        st.x = *reinterpret_cast<unsigned*>(&h01);
        st.y = *reinterpret_cast<unsigned*>(&h23);
        ((uint2*)H16)[(size_t)row * 16 + tc] = st;
      }
    }
  }
}

// ---------------- build: in-LDS counting sort of dense bucket segments ----------------

__global__ __launch_bounds__(256) void k_build(unsigned* __restrict__ packed,
                                               const int* __restrict__ T,
                                               const int* __restrict__ bbase,
                                               int2* __restrict__ rowrange,
                                               float* __restrict__ dis,
                                               int n, int nbuck) {
  __shared__ unsigned buf[CAPB];   // 16KB
  __shared__ unsigned outb[CAPB];  // 16KB
  __shared__ int cnt4[4][64];
  __shared__ int cur4[4][64];
  __shared__ int offi[64];
  __shared__ int offx[64];
  __shared__ int cntl[64];
  int b = blockIdx.x;
  int t = threadIdx.x;
  int g = t >> 6;
  int m = T[b];
  if (m > CAPB) m = CAPB;  // statistically unreachable (mean 2048, 8+ sd)
  int bb = bbase[b];
  unsigned* pb = packed + bb;

  cnt4[g][t & 63] = 0;
  for (int k = t; k < m; k += 256) buf[k] = pb[k];
  __syncthreads();
  for (int k = t; k < m; k += 256) atomicAdd(&cnt4[g][buf[k] & 63u], 1);
  __syncthreads();
  if (t < 64) {
    int c0 = cnt4[0][t], c1 = cnt4[1][t], c2 = cnt4[2][t], c3 = cnt4[3][t];
    int tot = c0 + c1 + c2 + c3;
    cntl[t] = tot;
    offi[t] = tot;
    cur4[0][t] = 0;
    cur4[1][t] = c0;
    cur4[2][t] = c0 + c1;
    cur4[3][t] = c0 + c1 + c2;
  }
  __syncthreads();
  for (int off = 1; off < 64; off <<= 1) {
    int x = (t < 64) ? offi[t] : 0;
    int y = (t >= off && t < 64) ? offi[t - off] : 0;
    __syncthreads();
    if (t < 64) offi[t] = x + y;
    __syncthreads();
  }
  if (t < 64) {
    offx[t] = offi[t] - cntl[t];
    int v = b * 64 + t;
    if (v < n) {
      rowrange[v] = make_int2(bb + offx[t], cntl[t]);
      dis[v] = rsqrtf((float)cntl[t] + 1.0f);  // +1 self-loop
    }
#pragma unroll
    for (int gg = 0; gg < 4; ++gg) cur4[gg][t] += offx[t];
  }
  __syncthreads();
  for (int k = t; k < m; k += 256) {
    unsigned e = buf[k];
    int dl = e & 63u;
    int q = atomicAdd(&cur4[g][dl], 1);
    outb[q] = e >> 6;
  }
  __syncthreads();
  for (int k = t; k < m; k += 256) pb[k] = outb[k];  // in place: packed becomes srcs
}

// ---------------- layer-1 agg: out = relu(dv*(sum dis[s]*h[s] + dv*h[v]) + b) ----------------

__global__ __launch_bounds__(256) void k_agg_w(const int2* __restrict__ rowrange,
                                               const int* __restrict__ srcs,
                                               const __half* __restrict__ g16,
                                               const float* __restrict__ dis,
                                               const float* __restrict__ bias,
                                               float* __restrict__ outp, int n) {
  int v = blockIdx.x * 16 + (threadIdx.x >> 4);
  if (v >= n) return;
  int lane = threadIdx.x & 15;
  int2 rr = rowrange[v];
  int j = rr.x, end = rr.x + rr.y;
  const uint2* g2 = (const uint2*)g16;

  float dv = dis[v];
  uint2 su = g2[(size_t)v * 16 + lane];
  float2 f0 = __half22float2(*reinterpret_cast<__half2*>(&su.x));
  float2 f1 = __half22float2(*reinterpret_cast<__half2*>(&su.y));
  float ax = dv * f0.x, ay = dv * f0.y, az = dv * f1.x, aw = dv * f1.y;

  for (; j + 8 <= end; j += 8) {
    int s[8];
#pragma unroll
    for (int q = 0; q < 8; ++q) s[q] = __builtin_nontemporal_load(&srcs[j + q]);
    float ds[8];
    uint2 a[8];
#pragma unroll
    for (int q = 0; q < 8; ++q) { ds[q] = dis[s[q]]; a[q] = g2[(size_t)s[q] * 16 + lane]; }
#pragma unroll
    for (int q = 0; q < 8; ++q) {
      float2 p0 = __half22float2(*reinterpret_cast<__half2*>(&a[q].x));
      float2 p1 = __half22float2(*reinterpret_cast<__half2*>(&a[q].y));
      ax = fmaf(ds[q], p0.x, ax); ay = fmaf(ds[q], p0.y, ay);
      az = fmaf(ds[q], p1.x, az); aw = fmaf(ds[q], p1.y, aw);
    }
  }
  for (; j < end; ++j) {
    int s0 = __builtin_nontemporal_load(&srcs[j]);
    float ds = dis[s0];
    uint2 a0 = g2[(size_t)s0 * 16 + lane];
    float2 p0 = __half22float2(*reinterpret_cast<__half2*>(&a0.x));
    float2 p1 = __half22float2(*reinterpret_cast<__half2*>(&a0.y));
    ax = fmaf(ds, p0.x, ax); ay = fmaf(ds, p0.y, ay);
    az = fmaf(ds, p1.x, az); aw = fmaf(ds, p1.y, aw);
  }

  float4 bb = *(const float4*)&bias[lane * 4];
  float4 o;
  o.x = fmaxf(fmaf(dv, ax, bb.x), 0.f);
  o.y = fmaxf(fmaf(dv, ay, bb.y), 0.f);
  o.z = fmaxf(fmaf(dv, az, bb.z), 0.f);
  o.w = fmaxf(fmaf(dv, aw, bb.w), 0.f);
  ((float4*)outp)[(size_t)v * 16 + lane] = o;
}

// ---------------- GEMM (layer 2): G16 = fp16(dis * (A @ W)), K=64 ----------------

template<int K>
__global__ __launch_bounds__(256) void k_gemm_scaled(const float* __restrict__ X,
                                                     const float* __restrict__ W,
                                                     const float* __restrict__ dis,
                                                     __half* __restrict__ G16, int n) {
  __shared__ float Wl[64 * 64];
  __shared__ float Xl[64 * 64];
  const int tid = threadIdx.x;
  const int row0 = blockIdx.x * 64;
  const int tc = tid & 15;
  const int tr = tid >> 4;
  float acc[4][4] = {};

  for (int k0 = 0; k0 < K; k0 += 64) {
    __syncthreads();
#pragma unroll
    for (int i = 0; i < 4; ++i) {
      int idx = tid * 4 + i * 1024;
      int kr = idx >> 6, c = idx & 63;
      *(vf4*)&Wl[idx] = *(const vf4*)&W[(size_t)(k0 + kr) * 64 + c];
    }
#pragma unroll
    for (int i = 0; i < 4; ++i) {
      int idx = tid * 4 + i * 1024;
      int r = idx >> 6, c = idx & 63;
      int row = row0 + r;
      vf4 v = {0.f, 0.f, 0.f, 0.f};
      if (row < n) v = __builtin_nontemporal_load((const vf4*)&X[(size_t)row * K + k0 + c]);
      *(vf4*)&Xl[idx] = v;
    }
    __syncthreads();
#pragma unroll 4
    for (int kk = 0; kk < 64; kk += 4) {
      float4 xv[4], wv[4];
#pragma unroll
      for (int r = 0; r < 4; ++r) xv[r] = *(float4*)&Xl[(tr * 4 + r) * 64 + kk];
#pragma unroll
      for (int q = 0; q < 4; ++q) wv[q] = *(float4*)&Wl[(kk + q) * 64 + tc * 4];
#pragma unroll
      for (int r = 0; r < 4; ++r) {
        const float xr[4] = {xv[r].x, xv[r].y, xv[r].z, xv[r].w};
#pragma unroll
        for (int q = 0; q < 4; ++q) {
          acc[r][0] += xr[q] * wv[q].x;
          acc[r][1] += xr[q] * wv[q].y;
          acc[r][2] += xr[q] * wv[q].z;
          acc[r][3] += xr[q] * wv[q].w;
        }
      }
    }
  }
#pragma unroll
  for (int r = 0; r < 4; ++r) {
    int row = row0 + tr * 4 + r;
    if (row < n) {
      float s = dis[row];
      __half2 h01 = __floats2half2_rn(acc[r][0] * s, acc[r][1] * s);
      __half2 h23 = __floats2half2_rn(acc[r][2] * s, acc[r][3] * s);
      uint2 st;
      st.x = *reinterpret_cast<unsigned*>(&h01);
      st.y = *reinterpret_cast<unsigned*>(&h23);
      ((uint2*)G16)[(size_t)row * 16 + tc] = st;
    }
  }
}

// ---------------- layer-2 agg (messages pre-scaled) ----------------

__global__ __launch_bounds__(256) void k_agg_csr(const int2* __restrict__ rowrange,
                                                 const int* __restrict__ srcs,
                                                 const __half* __restrict__ g16,
                                                 const float* __restrict__ dis,
                                                 const float* __restrict__ bias,
                                                 float* __restrict__ outp, int n) {
  int v = blockIdx.x * 16 + (threadIdx.x >> 4);
  if (v >= n) return;
  int lane = threadIdx.x & 15;
  int2 rr = rowrange[v];
  int j = rr.x, end = rr.x + rr.y;
  const uint2* g2 = (const uint2*)g16;

  uint2 su = g2[(size_t)v * 16 + lane];
  float2 f0 = __half22float2(*reinterpret_cast<__half2*>(&su.x));
  float2 f1 = __half22float2(*reinterpret_cast<__half2*>(&su.y));
  float ax = f0.x, ay = f0.y, az = f1.x, aw = f1.y;

  for (; j + 8 <= end; j += 8) {
    int s[8];
#pragma unroll
    for (int q = 0; q < 8; ++q) s[q] = __builtin_nontemporal_load(&srcs[j + q]);
    uint2 a[8];
#pragma unroll
    for (int q = 0; q < 8; ++q) a[q] = g2[(size_t)s[q] * 16 + lane];
#pragma unroll
    for (int q = 0; q < 8; ++q) {
      float2 p0 = __half22float2(*reinterpret_cast<__half2*>(&a[q].x));
      float2 p1 = __half22float2(*reinterpret_cast<__half2*>(&a[q].y));
      ax += p0.x; ay += p0.y; az += p1.x; aw += p1.y;
    }
  }
  for (; j < end; ++j) {
    int s0 = __builtin_nontemporal_load(&srcs[j]);
    uint2 a0 = g2[(size_t)s0 * 16 + lane];
    float2 p0 = __half22float2(*reinterpret_cast<__half2*>(&a0.x));
    float2 p1 = __half22float2(*reinterpret_cast<__half2*>(&a0.y));
    ax += p0.x; ay += p0.y; az += p1.x; aw += p1.y;
  }

  float dv = dis[v];
  float4 bb = *(const float4*)&bias[lane * 4];
  float4 o;
  o.x = fmaxf(fmaf(dv, ax, bb.x), 0.f);
  o.y = fmaxf(fmaf(dv, ay, bb.y), 0.f);
  o.z = fmaxf(fmaf(dv, az, bb.z), 0.f);
  o.w = fmaxf(fmaf(dv, aw, bb.w), 0.f);
  ((float4*)outp)[(size_t)v * 16 + lane] = o;
}

// ---------------- final FC ----------------

__global__ __launch_bounds__(256) void k_fc(const float* __restrict__ A,
                                            const float* __restrict__ Wfc,
                                            const float* __restrict__ bfc,
                                            float* __restrict__ outp, int n) {
  __shared__ float Wl[64 * NCLS];
  __shared__ float bl[8];
  int tid = threadIdx.x;
  for (int i = tid; i < 64 * NCLS; i += 256) Wl[i] = Wfc[i];
  if (tid < NCLS) bl[tid] = bfc[tid];
  __syncthreads();
  int row = blockIdx.x * 256 + tid;
  if (row >= n) return;
  float accv[NCLS];
#pragma unroll
  for (int j = 0; j < NCLS; ++j) accv[j] = bl[j];
  const vf4* a4 = (const vf4*)&A[(size_t)row * 64];
#pragma unroll
  for (int k4 = 0; k4 < 16; ++k4) {
    vf4 a = __builtin_nontemporal_load(&a4[k4]);
    const float av[4] = {a.x, a.y, a.z, a.w};
#pragma unroll
    for (int q = 0; q < 4; ++q)
#pragma unroll
      for (int j = 0; j < NCLS; ++j) accv[j] += av[q] * Wl[(k4 * 4 + q) * NCLS + j];
  }
#pragma unroll
  for (int j = 0; j < NCLS; ++j) outp[(size_t)row * NCLS + j] = accv[j];
}

// ---------------- launch ----------------

extern "C" void kernel_launch(void* const* d_in, const int* in_sizes, int n_in,
                              void* d_out, int out_size, void* d_ws, size_t ws_size,
                              hipStream_t stream) {
  const float* x   = (const float*)d_in[0];
  const int*   ei  = (const int*)d_in[1];
  const float* W1  = (const float*)d_in[2];
  const float* b1  = (const float*)d_in[3];
  const float* W2  = (const float*)d_in[4];
  const float* b2  = (const float*)d_in[5];
  const float* Wfc = (const float*)d_in[6];
  const float* bfc = (const float*)d_in[7];
  float* out = (float*)d_out;

  const int n = in_sizes[0] / NFEAT;   // 100000
  const int E = in_sizes[1] / 2;       // 3200000
  const int* src = ei;
  const int* dst = ei + E;
  const int nbuck = (n + 63) >> 6;     // 1563 (<= NBMX)
  const int nbb = (E + CHUNK - 1) / CHUNK;  // 196 count/scatter blocks
  const int ntile = (n + 63) / 64;     // 1563 gemm tiles

  char* ws = (char*)d_ws;
  size_t off = 0;
  auto alloc = [&](size_t bytes) -> void* {
    void* p = (void*)(ws + off);
    off += (bytes + 255) & ~(size_t)255;
    return p;
  };
  float* dis      = (float*)alloc((size_t)n * 4);
  int2*  rowrange = (int2*)alloc((size_t)n * 8);
  int*   C        = (int*)alloc((size_t)nbb * nbuck * 4);   // 1.2MB count matrix
  int*   T        = (int*)alloc((size_t)nbuck * 4);
  int*   bbase    = (int*)alloc((size_t)nbuck * 4);
  unsigned* packed = (unsigned*)alloc((size_t)E * 4);       // 12.8MB dense; becomes srcs
  __half* bufA16  = (__half*)alloc((size_t)n * HID * 2);    // 12.8MB
  float* bufB     = (float*)alloc((size_t)n * HID * 4);     // 25.6MB

  // ---- deterministic 3-pass CSR build; pass 3 runs || gemm1 ----
  k_count<<<nbb, 256, 0, stream>>>(dst, C, E, nbuck);
  k_scan_cols<<<(nbuck + 255) / 256, 256, 0, stream>>>(C, T, nbb, nbuck);
  k_scanb<<<1, 256, 0, stream>>>(T, bbase, nbuck);
  k_fused<<<nbb + ntile, 256, FUSED_LDS, stream>>>(src, dst, C, bbase, packed,
                                                   E, nbuck, nbb, x, W1, bufA16, n);
  k_build<<<nbuck, 256, 0, stream>>>(packed, T, bbase, rowrange, dis, n, nbuck);

  // ---- layer 1 aggregation (dis-weighted) ----
  k_agg_w<<<(n + 15) / 16, 256, 0, stream>>>(rowrange, (const int*)packed, bufA16, dis, b1, bufB, n);

  // ---- layer 2 ----
  k_gemm_scaled<HID><<<(n + 63) / 64, 256, 0, stream>>>(bufB, W2, dis, bufA16, n);
  k_agg_csr<<<(n + 15) / 16, 256, 0, stream>>>(rowrange, (const int*)packed, bufA16, dis, b2, bufB, n);

  // ---- FC head ----
  k_fc<<<(n + 255) / 256, 256, 0, stream>>>(bufB, Wfc, bfc, out, n);
}

// Round 15
// 286.219 us; speedup vs baseline: 1.3941x; 1.1091x over previous
//
#include <hip/hip_runtime.h>
#include <hip/hip_fp16.h>
#include <math.h>

#define NFEAT 256
#define HID 64
#define NCLS 6
#define NBMX 1600       // LDS sizing (nbuck = 1563)
#define CAPB 4096       // k_build LDS buffer bound (bucket mean 2048, 8+ sd headroom)
#define CHUNK 16384     // edges per count/scatter block
#define FUSED_LDS 32768 // gemm branch 32KB; scatter branch needs 12.8KB

typedef float vf4 __attribute__((ext_vector_type(4)));
typedef int   vi4 __attribute__((ext_vector_type(4)));

// ---------------- pass 1: per-block bucket histogram ----------------

__global__ __launch_bounds__(256) void k_count(const int* __restrict__ dst,
                                               int* __restrict__ C, int E, int nbuck) {
  __shared__ int cnt[NBMX];
  int t = threadIdx.x;
  for (int i = t; i < nbuck; i += 256) cnt[i] = 0;
  __syncthreads();
  int e0 = blockIdx.x * CHUNK;
  int e1 = e0 + CHUNK;
  if (e1 > E) e1 = E;
  for (int r0 = e0; r0 < e1; r0 += 1024) {
    int i0 = r0 + t * 4;
    if (i0 + 4 <= e1) {
      vi4 dv = __builtin_nontemporal_load((const vi4*)&dst[i0]);
      atomicAdd(&cnt[dv.x >> 6], 1);
      atomicAdd(&cnt[dv.y >> 6], 1);
      atomicAdd(&cnt[dv.z >> 6], 1);
      atomicAdd(&cnt[dv.w >> 6], 1);
    } else {
      for (int q = 0; q < 4; ++q)
        if (i0 + q < e1) atomicAdd(&cnt[dst[i0 + q] >> 6], 1);
    }
  }
  __syncthreads();
  int* Crow = C + (size_t)blockIdx.x * nbuck;
  for (int i = t; i < nbuck; i += 256) Crow[i] = cnt[i];
}

// ---------------- pass 2a: per-bucket column prefix over blocks ----------------

__global__ __launch_bounds__(256) void k_scan_cols(int* __restrict__ C,
                                                   int* __restrict__ T,
                                                   int nblk, int nbuck) {
  int b = blockIdx.x * 256 + threadIdx.x;
  if (b >= nbuck) return;
  int run = 0;
  int blk = 0;
  for (; blk + 4 <= nblk; blk += 4) {
    int c0 = C[(size_t)(blk + 0) * nbuck + b];
    int c1 = C[(size_t)(blk + 1) * nbuck + b];
    int c2 = C[(size_t)(blk + 2) * nbuck + b];
    int c3 = C[(size_t)(blk + 3) * nbuck + b];
    C[(size_t)(blk + 0) * nbuck + b] = run; run += c0;
    C[(size_t)(blk + 1) * nbuck + b] = run; run += c1;
    C[(size_t)(blk + 2) * nbuck + b] = run; run += c2;
    C[(size_t)(blk + 3) * nbuck + b] = run; run += c3;
  }
  for (; blk < nblk; ++blk) {
    int c = C[(size_t)blk * nbuck + b];
    C[(size_t)blk * nbuck + b] = run;
    run += c;
  }
  T[b] = run;
}

// ---------------- pass 2b: exclusive scan of T -> bbase ----------------

__global__ __launch_bounds__(256) void k_scanb(const int* __restrict__ T,
                                               int* __restrict__ bbase, int nbuck) {
  __shared__ int sh[256];
  __shared__ int carry;
  int t = threadIdx.x;
  if (t == 0) carry = 0;
  __syncthreads();
  for (int base = 0; base < nbuck; base += 256) {
    int v = (base + t < nbuck) ? T[base + t] : 0;
    sh[t] = v;
    __syncthreads();
    for (int off = 1; off < 256; off <<= 1) {
      int x = sh[t];
      int y = (t >= off) ? sh[t - off] : 0;
      __syncthreads();
      sh[t] = x + y;
      __syncthreads();
    }
    if (base + t < nbuck) bbase[base + t] = carry + sh[t] - v;
    __syncthreads();
    if (t == 255) carry += sh[255];
    __syncthreads();
  }
}

// ---------------- pass 3 FUSED: scatter (blocks < nbb) || GEMM1 unscaled ----------------

__global__ __launch_bounds__(256) void k_fused(const int* __restrict__ src,
                                               const int* __restrict__ dst,
                                               const int* __restrict__ C,
                                               const int* __restrict__ bbase,
                                               unsigned* __restrict__ packed,
                                               int E, int nbuck, int nbb,
                                               const float* __restrict__ X,
                                               const float* __restrict__ W1,
                                               __half* __restrict__ H16, int n) {
  extern __shared__ char smem[];
  int t = threadIdx.x;

  if (blockIdx.x < nbb) {
    int* baseL = (int*)smem;            // NBMX
    int* cnt   = baseL + NBMX;          // NBMX
    const int* Crow = C + (size_t)blockIdx.x * nbuck;
    for (int i = t; i < nbuck; i += 256) {
      baseL[i] = bbase[i] + Crow[i];
      cnt[i] = 0;
    }
    __syncthreads();

    int e0 = blockIdx.x * CHUNK;
    int e1 = e0 + CHUNK;
    if (e1 > E) e1 = E;
    for (int r0 = e0; r0 < e1; r0 += 1024) {
      int i0 = r0 + t * 4;
      int s4[4], d4[4];
      bool full = (i0 + 4 <= e1);
      if (full) {
        vi4 sv = __builtin_nontemporal_load((const vi4*)&src[i0]);
        vi4 dv = __builtin_nontemporal_load((const vi4*)&dst[i0]);
        s4[0] = sv.x; s4[1] = sv.y; s4[2] = sv.z; s4[3] = sv.w;
        d4[0] = dv.x; d4[1] = dv.y; d4[2] = dv.z; d4[3] = dv.w;
      } else {
        for (int q = 0; q < 4; ++q)
          if (i0 + q < e1) { s4[q] = src[i0 + q]; d4[q] = dst[i0 + q]; }
      }
#pragma unroll
      for (int q = 0; q < 4; ++q) {
        if (i0 + q < e1) {
          int b = d4[q] >> 6;
          int slot = atomicAdd(&cnt[b], 1);
          packed[(size_t)baseL[b] + slot] =
              ((unsigned)s4[q] << 6) | (unsigned)(d4[q] & 63);
        }
      }
    }
  } else {
    float* Wl = (float*)smem;          // 64*64
    float* Xl = Wl + 4096;             // 64*64
    const int row0 = (blockIdx.x - nbb) * 64;
    const int tc = t & 15;
    const int tr = t >> 4;
    float acc[4][4] = {};

    for (int k0 = 0; k0 < NFEAT; k0 += 64) {
      __syncthreads();
#pragma unroll
      for (int i = 0; i < 4; ++i) {
        int idx = t * 4 + i * 1024;
        int kr = idx >> 6, c = idx & 63;
        *(vf4*)&Wl[idx] = *(const vf4*)&W1[(size_t)(k0 + kr) * 64 + c];
      }
#pragma unroll
      for (int i = 0; i < 4; ++i) {
        int idx = t * 4 + i * 1024;
        int r = idx >> 6, c = idx & 63;
        int row = row0 + r;
        vf4 v = {0.f, 0.f, 0.f, 0.f};
        if (row < n) v = __builtin_nontemporal_load((const vf4*)&X[(size_t)row * NFEAT + k0 + c]);
        *(vf4*)&Xl[idx] = v;
      }
      __syncthreads();
#pragma unroll 4
      for (int kk = 0; kk < 64; kk += 4) {
        float4 xv[4], wv[4];
#pragma unroll
        for (int r = 0; r < 4; ++r) xv[r] = *(float4*)&Xl[(tr * 4 + r) * 64 + kk];
#pragma unroll
        for (int q = 0; q < 4; ++q) wv[q] = *(float4*)&Wl[(kk + q) * 64 + tc * 4];
#pragma unroll
        for (int r = 0; r < 4; ++r) {
          const float xr[4] = {xv[r].x, xv[r].y, xv[r].z, xv[r].w};
#pragma unroll
          for (int q = 0; q < 4; ++q) {
            acc[r][0] += xr[q] * wv[q].x;
            acc[r][1] += xr[q] * wv[q].y;
            acc[r][2] += xr[q] * wv[q].z;
            acc[r][3] += xr[q] * wv[q].w;
          }
        }
      }
    }
#pragma unroll
    for (int r = 0; r < 4; ++r) {
      int row = row0 + tr * 4 + r;
      if (row < n) {
        __half2 h01 = __floats2half2_rn(acc[r][0], acc[r][1]);
        __half2 h23 = __floats2half2_rn(acc[r][2], acc[r][3]);
        uint2 st;
        st.x = *reinterpret_cast<unsigned*>(&h01);
        st.y = *reinterpret_cast<unsigned*>(&h23);
        ((uint2*)H16)[(size_t)row * 16 + tc] = st;
      }
    }
  }
}

// ---------------- build: in-LDS counting sort of dense bucket segments ----------------

__global__ __launch_bounds__(256) void k_build(unsigned* __restrict__ packed,
                                               const int* __restrict__ T,
                                               const int* __restrict__ bbase,
                                               int2* __restrict__ rowrange,
                                               float* __restrict__ dis,
                                               int n, int nbuck) {
  __shared__ unsigned buf[CAPB];
  __shared__ unsigned outb[CAPB];
  __shared__ int cnt4[4][64];
  __shared__ int cur4[4][64];
  __shared__ int offi[64];
  __shared__ int offx[64];
  __shared__ int cntl[64];
  int b = blockIdx.x;
  int t = threadIdx.x;
  int g = t >> 6;
  int m = T[b];
  if (m > CAPB) m = CAPB;
  int bb = bbase[b];
  unsigned* pb = packed + bb;

  cnt4[g][t & 63] = 0;
  for (int k = t; k < m; k += 256) buf[k] = pb[k];
  __syncthreads();
  for (int k = t; k < m; k += 256) atomicAdd(&cnt4[g][buf[k] & 63u], 1);
  __syncthreads();
  if (t < 64) {
    int c0 = cnt4[0][t], c1 = cnt4[1][t], c2 = cnt4[2][t], c3 = cnt4[3][t];
    int tot = c0 + c1 + c2 + c3;
    cntl[t] = tot;
    offi[t] = tot;
    cur4[0][t] = 0;
    cur4[1][t] = c0;
    cur4[2][t] = c0 + c1;
    cur4[3][t] = c0 + c1 + c2;
  }
  __syncthreads();
  for (int off = 1; off < 64; off <<= 1) {
    int x = (t < 64) ? offi[t] : 0;
    int y = (t >= off && t < 64) ? offi[t - off] : 0;
    __syncthreads();
    if (t < 64) offi[t] = x + y;
    __syncthreads();
  }
  if (t < 64) {
    offx[t] = offi[t] - cntl[t];
    int v = b * 64 + t;
    if (v < n) {
      rowrange[v] = make_int2(bb + offx[t], cntl[t]);
      dis[v] = rsqrtf((float)cntl[t] + 1.0f);  // +1 self-loop
    }
#pragma unroll
    for (int gg = 0; gg < 4; ++gg) cur4[gg][t] += offx[t];
  }
  __syncthreads();
  for (int k = t; k < m; k += 256) {
    unsigned e = buf[k];
    int dl = e & 63u;
    int q = atomicAdd(&cur4[g][dl], 1);
    outb[q] = e >> 6;
  }
  __syncthreads();
  for (int k = t; k < m; k += 256) pb[k] = outb[k];  // packed becomes srcs
}

// ---------------- FUSED layer 1: agg (dis-weighted) + ReLU + @W2 + dis-scale -> g2 fp16 ----------------
// a1[v] = relu(dv*(sum dis[s]*h[s] + dv*h[v]) + b1);  g2[v] = fp16(dv * (a1[v] @ W2))

__global__ __launch_bounds__(256) void k_agg_gemm(const int2* __restrict__ rowrange,
                                                  const int* __restrict__ srcs,
                                                  const __half* __restrict__ g16,
                                                  const float* __restrict__ dis,
                                                  const float* __restrict__ b1,
                                                  const float* __restrict__ W2,
                                                  __half* __restrict__ g2out, int n) {
  __shared__ float W2l[64 * 64];   // 16KB
  __shared__ float arow[16][68];   // 4.3KB, pad 68 to stagger banks
  int t = threadIdx.x;
  for (int i = t * 4; i < 4096; i += 1024)
    *(vf4*)&W2l[i] = *(const vf4*)&W2[i];

  int grp = t >> 4, lane = t & 15;
  int v = blockIdx.x * 16 + grp;
  bool active = (v < n);
  const uint2* g2 = (const uint2*)g16;

  float rx = 0.f, ry = 0.f, rz = 0.f, rw = 0.f;
  if (active) {
    int2 rr = rowrange[v];
    int j = rr.x, end = rr.x + rr.y;
    float dv = dis[v];
    uint2 su = g2[(size_t)v * 16 + lane];
    float2 f0 = __half22float2(*reinterpret_cast<__half2*>(&su.x));
    float2 f1 = __half22float2(*reinterpret_cast<__half2*>(&su.y));
    float ax = dv * f0.x, ay = dv * f0.y, az = dv * f1.x, aw = dv * f1.y;

    for (; j + 8 <= end; j += 8) {
      int s[8];
#pragma unroll
      for (int q = 0; q < 8; ++q) s[q] = __builtin_nontemporal_load(&srcs[j + q]);
      float ds[8];
      uint2 a[8];
#pragma unroll
      for (int q = 0; q < 8; ++q) { ds[q] = dis[s[q]]; a[q] = g2[(size_t)s[q] * 16 + lane]; }
#pragma unroll
      for (int q = 0; q < 8; ++q) {
        float2 p0 = __half22float2(*reinterpret_cast<__half2*>(&a[q].x));
        float2 p1 = __half22float2(*reinterpret_cast<__half2*>(&a[q].y));
        ax = fmaf(ds[q], p0.x, ax); ay = fmaf(ds[q], p0.y, ay);
        az = fmaf(ds[q], p1.x, az); aw = fmaf(ds[q], p1.y, aw);
      }
    }
    for (; j < end; ++j) {
      int s0 = __builtin_nontemporal_load(&srcs[j]);
      float ds = dis[s0];
      uint2 a0 = g2[(size_t)s0 * 16 + lane];
      float2 p0 = __half22float2(*reinterpret_cast<__half2*>(&a0.x));
      float2 p1 = __half22float2(*reinterpret_cast<__half2*>(&a0.y));
      ax = fmaf(ds, p0.x, ax); ay = fmaf(ds, p0.y, ay);
      az = fmaf(ds, p1.x, az); aw = fmaf(ds, p1.y, aw);
    }
    float4 bb = *(const float4*)&b1[lane * 4];
    rx = fmaxf(fmaf(dv, ax, bb.x), 0.f);
    ry = fmaxf(fmaf(dv, ay, bb.y), 0.f);
    rz = fmaxf(fmaf(dv, az, bb.z), 0.f);
    rw = fmaxf(fmaf(dv, aw, bb.w), 0.f);
  }
  arow[grp][lane * 4 + 0] = rx;
  arow[grp][lane * 4 + 1] = ry;
  arow[grp][lane * 4 + 2] = rz;
  arow[grp][lane * 4 + 3] = rw;
  __syncthreads();

  if (active) {
    float o0 = 0.f, o1 = 0.f, o2 = 0.f, o3 = 0.f;
    int c = lane * 4;
#pragma unroll 4
    for (int k = 0; k < 64; ++k) {
      float a = arow[grp][k];
      vf4 w = *(const vf4*)&W2l[k * 64 + c];
      o0 = fmaf(a, w.x, o0);
      o1 = fmaf(a, w.y, o1);
      o2 = fmaf(a, w.z, o2);
      o3 = fmaf(a, w.w, o3);
    }
    float dvv = dis[v];
    __half2 h01 = __floats2half2_rn(o0 * dvv, o1 * dvv);
    __half2 h23 = __floats2half2_rn(o2 * dvv, o3 * dvv);
    uint2 st;
    st.x = *reinterpret_cast<unsigned*>(&h01);
    st.y = *reinterpret_cast<unsigned*>(&h23);
    ((uint2*)g2out)[(size_t)v * 16 + lane] = st;
  }
}

// ---------------- FUSED layer 2: agg (pre-scaled msgs) + ReLU + @Wfc + bfc -> out ----------------

__global__ __launch_bounds__(256) void k_agg_fc(const int2* __restrict__ rowrange,
                                                const int* __restrict__ srcs,
                                                const __half* __restrict__ g16,
                                                const float* __restrict__ dis,
                                                const float* __restrict__ b2,
                                                const float* __restrict__ Wfc,
                                                const float* __restrict__ bfc,
                                                float* __restrict__ outp, int n) {
  __shared__ float Wl[64 * NCLS];  // 1.5KB
  __shared__ float bl[8];
  int t = threadIdx.x;
  for (int i = t; i < 64 * NCLS; i += 256) Wl[i] = Wfc[i];
  if (t < NCLS) bl[t] = bfc[t];
  __syncthreads();

  int grp = t >> 4, lane = t & 15;
  int v = blockIdx.x * 16 + grp;
  bool active = (v < n);
  const uint2* g2 = (const uint2*)g16;

  float r0 = 0.f, r1 = 0.f, r2 = 0.f, r3 = 0.f;
  if (active) {
    int2 rr = rowrange[v];
    int j = rr.x, end = rr.x + rr.y;
    uint2 su = g2[(size_t)v * 16 + lane];
    float2 f0 = __half22float2(*reinterpret_cast<__half2*>(&su.x));
    float2 f1 = __half22float2(*reinterpret_cast<__half2*>(&su.y));
    float ax = f0.x, ay = f0.y, az = f1.x, aw = f1.y;

    for (; j + 8 <= end; j += 8) {
      int s[8];
#pragma unroll
      for (int q = 0; q < 8; ++q) s[q] = __builtin_nontemporal_load(&srcs[j + q]);
      uint2 a[8];
#pragma unroll
      for (int q = 0; q < 8; ++q) a[q] = g2[(size_t)s[q] * 16 + lane];
#pragma unroll
      for (int q = 0; q < 8; ++q) {
        float2 p0 = __half22float2(*reinterpret_cast<__half2*>(&a[q].x));
        float2 p1 = __half22float2(*reinterpret_cast<__half2*>(&a[q].y));
        ax += p0.x; ay += p0.y; az += p1.x; aw += p1.y;
      }
    }
    for (; j < end; ++j) {
      int s0 = __builtin_nontemporal_load(&srcs[j]);
      uint2 a0 = g2[(size_t)s0 * 16 + lane];
      float2 p0 = __half22float2(*reinterpret_cast<__half2*>(&a0.x));
      float2 p1 = __half22float2(*reinterpret_cast<__half2*>(&a0.y));
      ax += p0.x; ay += p0.y; az += p1.x; aw += p1.y;
    }
    float dv = dis[v];
    float4 bb = *(const float4*)&b2[lane * 4];
    r0 = fmaxf(fmaf(dv, ax, bb.x), 0.f);
    r1 = fmaxf(fmaf(dv, ay, bb.y), 0.f);
    r2 = fmaxf(fmaf(dv, az, bb.z), 0.f);
    r3 = fmaxf(fmaf(dv, aw, bb.w), 0.f);
  }

  // partial FC: lane holds cols 4*lane..4*lane+3 of a2
  float p[NCLS];
#pragma unroll
  for (int jj = 0; jj < NCLS; ++jj) p[jj] = 0.f;
  int k0 = lane * 4;
#pragma unroll
  for (int q = 0; q < 4; ++q) {
    float a = (q == 0) ? r0 : (q == 1) ? r1 : (q == 2) ? r2 : r3;
#pragma unroll
    for (int jj = 0; jj < NCLS; ++jj)
      p[jj] = fmaf(a, Wl[(k0 + q) * NCLS + jj], p[jj]);
  }
  // reduce across the 16-lane group
#pragma unroll
  for (int m = 1; m < 16; m <<= 1) {
#pragma unroll
    for (int jj = 0; jj < NCLS; ++jj)
      p[jj] += __shfl_xor(p[jj], m, 64);
  }
  if (active && lane < NCLS)
    outp[(size_t)v * NCLS + lane] = p[lane] + bl[lane];
}

// ---------------- launch ----------------

extern "C" void kernel_launch(void* const* d_in, const int* in_sizes, int n_in,
                              void* d_out, int out_size, void* d_ws, size_t ws_size,
                              hipStream_t stream) {
  const float* x   = (const float*)d_in[0];
  const int*   ei  = (const int*)d_in[1];
  const float* W1  = (const float*)d_in[2];
  const float* b1  = (const float*)d_in[3];
  const float* W2  = (const float*)d_in[4];
  const float* b2  = (const float*)d_in[5];
  const float* Wfc = (const float*)d_in[6];
  const float* bfc = (const float*)d_in[7];
  float* out = (float*)d_out;

  const int n = in_sizes[0] / NFEAT;   // 100000
  const int E = in_sizes[1] / 2;       // 3200000
  const int* src = ei;
  const int* dst = ei + E;
  const int nbuck = (n + 63) >> 6;     // 1563 (<= NBMX)
  const int nbb = (E + CHUNK - 1) / CHUNK;  // 196 count/scatter blocks
  const int ntile = (n + 63) / 64;     // 1563 gemm tiles

  char* ws = (char*)d_ws;
  size_t off = 0;
  auto alloc = [&](size_t bytes) -> void* {
    void* p = (void*)(ws + off);
    off += (bytes + 255) & ~(size_t)255;
    return p;
  };
  float* dis      = (float*)alloc((size_t)n * 4);
  int2*  rowrange = (int2*)alloc((size_t)n * 8);
  int*   C        = (int*)alloc((size_t)nbb * nbuck * 4);   // 1.2MB count matrix
  int*   T        = (int*)alloc((size_t)nbuck * 4);
  int*   bbase    = (int*)alloc((size_t)nbuck * 4);
  unsigned* packed = (unsigned*)alloc((size_t)E * 4);       // 12.8MB dense; becomes srcs
  __half* bufA16  = (__half*)alloc((size_t)n * HID * 2);    // g1 (12.8MB)
  __half* bufC16  = (__half*)alloc((size_t)n * HID * 2);    // g2 (12.8MB)

  // ---- deterministic 3-pass CSR build; pass 3 runs || gemm1 ----
  k_count<<<nbb, 256, 0, stream>>>(dst, C, E, nbuck);
  k_scan_cols<<<(nbuck + 255) / 256, 256, 0, stream>>>(C, T, nbb, nbuck);
  k_scanb<<<1, 256, 0, stream>>>(T, bbase, nbuck);
  k_fused<<<nbb + ntile, 256, FUSED_LDS, stream>>>(src, dst, C, bbase, packed,
                                                   E, nbuck, nbb, x, W1, bufA16, n);
  k_build<<<nbuck, 256, 0, stream>>>(packed, T, bbase, rowrange, dis, n, nbuck);

  // ---- layer 1 agg + gemm2 fused -> g2 ----
  k_agg_gemm<<<(n + 15) / 16, 256, 0, stream>>>(rowrange, (const int*)packed, bufA16,
                                                dis, b1, W2, bufC16, n);

  // ---- layer 2 agg + FC fused -> out ----
  k_agg_fc<<<(n + 15) / 16, 256, 0, stream>>>(rowrange, (const int*)packed, bufC16,
                                              dis, b2, Wfc, bfc, out, n);
}